// Round 11
// baseline (184.976 us; speedup 1.0000x reference)
//
#include <hip/hip_runtime.h>
#include <hip/hip_bf16.h>
#include <math.h>

#define HH 128
#define WW 128
#define HW 16384
#define BB 2
#define CC 192

typedef __attribute__((ext_vector_type(8)))  short short8;
typedef __attribute__((ext_vector_type(4)))  float f32x4;
typedef __attribute__((ext_vector_type(16))) float f32x16;
typedef __attribute__((ext_vector_type(2)))  float f32x2;
typedef __attribute__((ext_vector_type(4)))  unsigned u32x4;

// f32 -> bf16 bits, round-to-nearest-even
static __device__ __forceinline__ short f2bf(float f) {
    unsigned u = __float_as_uint(f);
    unsigned r = (u + 0x7FFFu + ((u >> 16) & 1u)) >> 16;
    return (short)r;
}
// u32 of 2 bf16 -> f32x2 {lo, hi}
static __device__ __forceinline__ f32x2 unpk(unsigned u) {
    f32x2 r;
    r[0] = __uint_as_float(u << 16);
    r[1] = __uint_as_float(u & 0xFFFF0000u);
    return r;
}

// async global->LDS, 16B per lane. lds dest: wave-uniform base + lane*16.
static __device__ __forceinline__ void gl_lds16(const short* gsrc, short* ldst) {
    __builtin_amdgcn_global_load_lds(
        (const __attribute__((address_space(1))) unsigned*)gsrc,
        (__attribute__((address_space(3))) unsigned*)ldst, 16, 0, 0);
}

// ---------------------------------------------------------------------------
// Grouped channels-last transpose: xg[b][cg(48)][pos][8ch] bf16.
// ---------------------------------------------------------------------------
__global__ __launch_bounds__(256) void to_grp_k(
    const float* __restrict__ xv, const float* __restrict__ xr,
    unsigned short* __restrict__ xg)
{
    const int idx = blockIdx.x * 256 + threadIdx.x;   // (b*48+cg)*HW + pos
    const int pos = idx & (HW - 1);
    const int cgb = idx >> 14;
    const int cg  = cgb % 48;
    const int b   = cgb / 48;
    short8 v;
#pragma unroll
    for (int r = 0; r < 8; r++) {
        const int c = cg * 8 + r;
        const float f = (c < 192)
            ? xv[((size_t)(b * 192 + c) << 14) + pos]
            : xr[((size_t)(b * 192 + (c - 192)) << 14) + pos];
        v[r] = f2bf(f);
    }
    *reinterpret_cast<short8*>(xg + (size_t)idx * 8) = v;
}

// ---------------------------------------------------------------------------
// Pack f32 weights into 32x32x16 A-frag chunks of 8 KB:
// wp[chunk*4096 + slot*512 + lane*8 + r], o = slot*32+(lane&31),
// k = chunk*16 + (lane>>5)*8 + r; src = w[o*so + (k/d1)*s1
//      + ((k%d1)/d2)*s2 + ((k%d1)%d2)*s3]. Zero-pad o >= Co.
// ---------------------------------------------------------------------------
__global__ void pack_w_k(const float* __restrict__ w, short* __restrict__ wp,
                         int Co, int so, int d1, int s1, int d2, int s2, int s3,
                         int total)
{
    const int idx = blockIdx.x * blockDim.x + threadIdx.x;
    if (idx >= total) return;
    const int lane  = idx & 63;
    const int slot  = (idx >> 6) & 7;
    const int chunk = idx >> 9;
    const int o     = slot * 32 + (lane & 31);
    const int k0    = chunk * 16 + ((lane >> 5) << 3);
    short8 v;
#pragma unroll
    for (int r = 0; r < 8; r++) {
        const int k = k0 + r;
        float f = 0.f;
        if (o < Co) {
            const int rem = k % d1;
            f = w[(size_t)o * so + (k / d1) * s1 + (rem / d2) * s2 + (rem % d2) * s3];
        }
        v[r] = f2bf(f);
    }
    *reinterpret_cast<short8*>(wp + (size_t)idx * 8) = v;
}

// ---------------------------------------------------------------------------
// 3x3 conv (pad 1), implicit GEMM, 32x32x16 MFMA, grouped-CL input.
// Block = 256 thr (4 waves: mg=wid>>1, nt=wid&1) computing a FULL ROW:
// 128 px x (MTW*2*32) out ch; grid = HH*BB = 256 -> 1 block/CU. A staged
// once per chunk per block (halved L2 A-traffic vs 64-px). Wave: MTW m-tiles
// x 2 n-tiles (px = nt*64 + nn*32). Two chunks per barrier, 3 pair-buffers,
// B 3-set x 4-reg rotation. Exact vmcnt: per pair in flight after issue =
// B(p+1)4 + S(p+1)(2*NSTG) + B(p+2)4 -> vmcnt(12) conv1 / vmcnt(10) conv2.
// conv2 (MTW=2) stages only slots 0..3 (4 KB).
// ---------------------------------------------------------------------------
template<int MTW, int NC16, bool OUT_GRP>
__global__ __launch_bounds__(256, 1) void conv_g_k(
    const unsigned short* __restrict__ xg,
    const short* __restrict__ wA, const float* __restrict__ bias,
    void* __restrict__ outp, int Cout)
{
    __shared__ __align__(16) short Pbuf[3][2][4096];

    const int t    = threadIdx.x;
    const int lane = t & 63;
    const int wid  = t >> 6;
    const int mg   = wid >> 1;
    const int nt   = wid & 1;
    // XCD swizzle over 256 blocks
    const int lin  = blockIdx.y * HH + blockIdx.x;
    const int og_  = (lin & 7) * 32 + (lin >> 3);
    const int i    = og_ & (HH - 1);
    const int b    = og_ >> 7;
    const int pxb  = nt * 64 + (lane & 31);
    const int hi   = lane >> 5;
    constexpr int NQ = NC16 * 9;
    constexpr int NP = NQ / 2;           // pairs, divisible by 3

    const unsigned short* __restrict__ xgb = xg + (size_t)b * (NC16 * 2) * HW * 8;

    f32x16 acc[MTW][2];
#pragma unroll
    for (int m = 0; m < MTW; m++)
#pragma unroll
        for (int n = 0; n < 2; n++)
#pragma unroll
            for (int r = 0; r < 16; r++) acc[m][n][r] = 0.f;

    // load B frag for chunk qq, n-subtile nn (px = pxb + nn*32)
    auto loadB = [&](int qq, int nn, short8& dst, bool& vm) {
        const int c16 = qq / 9;
        const int tap = qq - c16 * 9;
        const int iy  = i + tap / 3 - 1;
        const int jx  = pxb + nn * 32 + tap % 3 - 1;
        vm = ((unsigned)iy < HH) && ((unsigned)jx < WW);
        const int iyc = min(max(iy, 0), HH - 1);
        const int jxc = min(max(jx, 0), WW - 1);
        dst = *reinterpret_cast<const short8*>(
            xgb + ((size_t)(c16 * 2 + hi) * HW + (iyc << 7) + jxc) * 8);
    };
    // stage one chunk into Pbuf[pb][sl]: NSTG gl_lds per thread
    auto stage = [&](int chunk, int pb, int sl) {
        gl_lds16(wA + (size_t)chunk * 4096 + t * 8, &Pbuf[pb][sl][wid * 512]);
        if constexpr (MTW >= 3)
            gl_lds16(wA + (size_t)chunk * 4096 + (t + 256) * 8,
                     &Pbuf[pb][sl][2048 + wid * 512]);
    };
    // loads for pair P into B-set (4 regs: chunk-in-pair x nn)
    auto loadB4 = [&](int P, short8* Bset, bool* Mset) {
        loadB(min(2 * P,     NQ - 1), 0, Bset[0], Mset[0]);
        loadB(min(2 * P,     NQ - 1), 1, Bset[1], Mset[1]);
        loadB(min(2 * P + 1, NQ - 1), 0, Bset[2], Mset[2]);
        loadB(min(2 * P + 1, NQ - 1), 1, Bset[3], Mset[3]);
    };

    short8 Bs0[4], Bs1[4], Bs2[4];
    bool   Ms0[4], Ms1[4], Ms2[4];

    // prologue: S(p0), B(p0), S(p1), B(p1)
    stage(0, 0, 0); stage(1, 0, 1);
    loadB4(0, Bs0, Ms0);
    stage(2, 1, 0); stage(3, 1, 1);
    loadB4(1, Bs1, Ms1);

#define CCHUNK(IBUF, SL, Bset, Mset, O)                                       \
    {                                                                         \
        short8 bF0 = Bset[(O) + 0];                                           \
        short8 bF1 = Bset[(O) + 1];                                           \
        if (!Mset[(O) + 0]) { _Pragma("unroll")                               \
            for (int r = 0; r < 8; r++) bF0[r] = 0; }                         \
        if (!Mset[(O) + 1]) { _Pragma("unroll")                               \
            for (int r = 0; r < 8; r++) bF1[r] = 0; }                         \
        const short* ab_ = &Pbuf[IBUF][SL][(mg * MTW) * 512 + lane * 8];      \
        short8 aF[MTW];                                                       \
        _Pragma("unroll")                                                     \
        for (int m = 0; m < MTW; m++)                                         \
            aF[m] = *reinterpret_cast<const short8*>(ab_ + m * 512);          \
        _Pragma("unroll")                                                     \
        for (int m = 0; m < MTW; m++) {                                       \
            acc[m][0] = __builtin_amdgcn_mfma_f32_32x32x16_bf16(aF[m], bF0, acc[m][0], 0, 0, 0); \
            acc[m][1] = __builtin_amdgcn_mfma_f32_32x32x16_bf16(aF[m], bF1, acc[m][1], 0, 0, 0); \
        }                                                                     \
    }

#define PSTEP(P, IBUF, SBUF, Bc, Mc, Bn, Mn)                                  \
    {                                                                         \
        loadB4(min((P) + 2, NP - 1), Bn, Mn);                                 \
        if constexpr (MTW >= 3) {                                             \
            asm volatile("s_waitcnt vmcnt(12)" ::: "memory");                 \
        } else {                                                              \
            asm volatile("s_waitcnt vmcnt(10)" ::: "memory");                 \
        }                                                                     \
        __builtin_amdgcn_s_barrier();                                         \
        __builtin_amdgcn_sched_barrier(0);                                    \
        const int p2_ = min((P) + 2, NP - 1);                                 \
        stage(min(2 * p2_,     NQ - 1), SBUF, 0);                             \
        stage(min(2 * p2_ + 1, NQ - 1), SBUF, 1);                             \
        CCHUNK(IBUF, 0, Bc, Mc, 0);                                           \
        CCHUNK(IBUF, 1, Bc, Mc, 2);                                           \
    }

    for (int pp = 0; pp < NP; pp += 3) {
        PSTEP(pp + 0, 0, 2, Bs0, Ms0, Bs2, Ms2);
        PSTEP(pp + 1, 1, 0, Bs1, Ms1, Bs0, Ms0);
        PSTEP(pp + 2, 2, 1, Bs2, Ms2, Bs1, Ms1);
    }
#undef PSTEP
#undef CCHUNK

    // store. C/D: col = lane&31 -> px ; row = (reg&3)+8*(reg>>2)+4*hi -> o.
#pragma unroll
    for (int nn = 0; nn < 2; nn++) {
        const int pos_o = (i << 7) + pxb + nn * 32;
        if constexpr (OUT_GRP) {
            unsigned short* fg = (unsigned short*)outp;
#pragma unroll
            for (int m = 0; m < MTW; m++) {
                const int mt32 = mg * MTW + m;
#pragma unroll
                for (int g = 0; g < 4; g++) {
                    const int ob = mt32 * 32 + 8 * g + 4 * hi;
                    const unsigned s0 = (unsigned short)f2bf(acc[m][nn][4 * g + 0] + bias[ob + 0]);
                    const unsigned s1 = (unsigned short)f2bf(acc[m][nn][4 * g + 1] + bias[ob + 1]);
                    const unsigned s2 = (unsigned short)f2bf(acc[m][nn][4 * g + 2] + bias[ob + 2]);
                    const unsigned s3 = (unsigned short)f2bf(acc[m][nn][4 * g + 3] + bias[ob + 3]);
                    const int cg = mt32 * 4 + g;
                    *reinterpret_cast<uint2*>(
                        fg + ((size_t)(b * (Cout >> 3) + cg) * HW + pos_o) * 8 + 4 * hi) =
                        make_uint2(s0 | (s1 << 16), s2 | (s3 << 16));
                }
            }
        } else {
            float* of = (float*)outp;
#pragma unroll
            for (int m = 0; m < MTW; m++) {
                const int mt32 = mg * MTW + m;
#pragma unroll
                for (int reg = 0; reg < 16; reg++) {
                    const int o = mt32 * 32 + (reg & 3) + ((reg >> 2) << 3) + (hi << 2);
                    if (o < Cout)
                        of[((size_t)(b * Cout + o) << 14) + pos_o] = acc[m][nn][reg] + bias[o];
                }
            }
        }
    }
}

// ---------------------------------------------------------------------------
// Fused deform-sample + einsum, 32x32x16 MFMA, producer-split bF sharing.
// Block = 256 thr (4 waves: nh = wid>>1 px-half, mh = wid&1 m-half/producer),
// 64 px x 192 out-ch; grid 512 -> 2 blocks/CU. Pair scheme: wave (mh,nh)
// gathers+combines chunk 2P+mh for px-half nh, writes bF to double-buffered
// LDS; one raw s_barrier per pair; every wave then MFMAs both sub-chunks for
// its (mh, nh) tile. A-fragment loads amortized over 64 px (halved L2
// A-traffic); waves (mh,0)/(mh,1) read identical A addresses (L1 dedup).
// Per pair per wave issue: 4 G + 6 A -> exact vmcnt(10).
// ---------------------------------------------------------------------------
__global__ __launch_bounds__(256, 2) void dcn_g_k(
    const unsigned short* __restrict__ xg, const float* __restrict__ off,
    const short* __restrict__ wA, const float* __restrict__ bias,
    float* __restrict__ out)
{
    __shared__ __align__(16) f32x4 eW[2304];          // 36 KB (36 gk x 64 px)
    __shared__ __align__(8)  uint2 eO[2304];          // 18 KB
    __shared__ __align__(16) short bfS[2][2][2][512]; //  8 KB [buf][sub][nh][.]

    const int t    = threadIdx.x;
    const int lane = t & 63;
    const int wid  = t >> 6;
    const int nh   = wid >> 1;   // px half
    const int mh   = wid & 1;    // m half = producer sub-chunk
    // XCD swizzle: nwg = 2*HH*BB = 512
    const int lin  = (blockIdx.z * HH + blockIdx.y) * 2 + blockIdx.x;
    const int og_  = (lin & 7) * 64 + (lin >> 3);
    const int j0   = (og_ & 1) * 64;
    const int i    = (og_ >> 1) & (HH - 1);
    const int b    = og_ >> 8;

    // ---- A1: bilinear entries (identical math to verified rounds 2-10) ----
    for (int e = t; e < 2304; e += 256) {
        const int p  = e & 63;
        const int gk = e >> 6;               // g*9 + kt
        const int kt = gk % 9;
        const int j  = j0 + p;
        const size_t sp = (size_t)b * 108 * HW + (size_t)gk * HW + (i << 7) + j;
        const float dy = off[sp];
        const float dx = off[sp + (size_t)36 * HW];
        const float mv = off[sp + (size_t)72 * HW];
        const float m  = 1.f / (1.f + expf(-mv));
        const float py = (float)(i + kt / 3 - 1) + dy;
        const float px = (float)(j + kt % 3 - 1) + dx;
        const float y0f = floorf(py), x0f = floorf(px);
        const float ly = py - y0f, lx = px - x0f;
        const int y0 = (int)y0f, x0 = (int)x0f;
        const float vy0 = (y0 >= 0 && y0 < HH) ? 1.f : 0.f;
        const float vy1 = (y0 + 1 >= 0 && y0 + 1 < HH) ? 1.f : 0.f;
        const float vx0 = (x0 >= 0 && x0 < WW) ? 1.f : 0.f;
        const float vx1 = (x0 + 1 >= 0 && x0 + 1 < WW) ? 1.f : 0.f;
        f32x4 w4;
        w4[0] = (1.f - ly) * (1.f - lx) * m * vy0 * vx0;
        w4[1] = (1.f - ly) * lx         * m * vy0 * vx1;
        w4[2] = ly         * (1.f - lx) * m * vy1 * vx0;
        w4[3] = ly         * lx         * m * vy1 * vx1;
        const int yc0 = min(max(y0, 0), HH - 1);
        const int yc1 = min(max(y0 + 1, 0), HH - 1);
        const int xc0 = min(max(x0, 0), WW - 1);
        const int xc1 = min(max(x0 + 1, 0), WW - 1);
        eW[e] = w4;
        eO[e] = make_uint2((unsigned)((yc0 << 7) + xc0) | ((unsigned)((yc0 << 7) + xc1) << 16),
                           (unsigned)((yc1 << 7) + xc0) | ((unsigned)((yc1 << 7) + xc1) << 16));
    }
    __syncthreads();

    const int px_a = nh * 32 + (lane & 31);   // absolute px within 64
    const int hi   = lane >> 5;
    const unsigned short* __restrict__ xgb = xg + (size_t)b * 48 * HW * 8;

    f32x16 acc[3];
#pragma unroll
    for (int m = 0; m < 3; m++)
#pragma unroll
        for (int r = 0; r < 16; r++) acc[m][r] = 0.f;

    // my gather chunk for pair P is 2P + mh
#define GISSUE(QQ, N0, N1, N2, N3, WN)                                        \
    {                                                                         \
        const int qn_   = min((QQ), 107);                                     \
        const int c16n_ = qn_ / 9;                                            \
        const int ktn_  = qn_ - 9 * c16n_;                                    \
        const int e_    = ((c16n_ / 3) * 9 + ktn_) * 64 + px_a;               \
        const uint2 o_  = eO[e_];                                             \
        WN = eW[e_];                                                          \
        const unsigned short* base_ = xgb + (size_t)(c16n_ * 2 + hi) * (HW * 8); \
        N0 = *reinterpret_cast<const u32x4*>(base_ + (size_t)(o_.x & 0xFFFFu) * 8); \
        N1 = *reinterpret_cast<const u32x4*>(base_ + (size_t)(o_.x >> 16) * 8);     \
        N2 = *reinterpret_cast<const u32x4*>(base_ + (size_t)(o_.y & 0xFFFFu) * 8); \
        N3 = *reinterpret_cast<const u32x4*>(base_ + (size_t)(o_.y >> 16) * 8);     \
    }

    // A frags for pair P (chunks 2P, 2P+1), m-half mh: 6 b128 loads
#define AISSUE(PP, DST)                                                       \
    {                                                                         \
        const short* a0_ = wA + (size_t)min(2 * (PP),     107) * 4096 + (mh * 3) * 512 + lane * 8; \
        const short* a1_ = wA + (size_t)min(2 * (PP) + 1, 107) * 4096 + (mh * 3) * 512 + lane * 8; \
        DST[0] = *reinterpret_cast<const short8*>(a0_);                       \
        DST[1] = *reinterpret_cast<const short8*>(a0_ + 512);                 \
        DST[2] = *reinterpret_cast<const short8*>(a0_ + 1024);                \
        DST[3] = *reinterpret_cast<const short8*>(a1_);                       \
        DST[4] = *reinterpret_cast<const short8*>(a1_ + 512);                 \
        DST[5] = *reinterpret_cast<const short8*>(a1_ + 1024);                \
    }

#define PAIRSTEP(P, Ac, C0, C1, C2, C3, WC, An, N0, N1, N2, N3, WN)           \
    {                                                                         \
        GISSUE(2 * ((P) + 1) + mh, N0, N1, N2, N3, WN);                       \
        AISSUE((P) + 1, An);                                                  \
        asm volatile("s_waitcnt vmcnt(10)" ::: "memory");                     \
        u32x4 rv_;                                                            \
        _Pragma("unroll")                                                     \
        for (int jj = 0; jj < 4; jj++) {                                      \
            f32x2 v_ = WC[0] * unpk(C0[jj]) + WC[1] * unpk(C1[jj])            \
                     + WC[2] * unpk(C2[jj]) + WC[3] * unpk(C3[jj]);           \
            __hip_bfloat162 h2_ = __float22bfloat162_rn(make_float2(v_[0], v_[1])); \
            unsigned hu_; __builtin_memcpy(&hu_, &h2_, 4);                    \
            rv_[jj] = hu_;                                                    \
        }                                                                     \
        *reinterpret_cast<u32x4*>(&bfS[(P) & 1][mh][nh][lane * 8]) = rv_;     \
        asm volatile("s_waitcnt lgkmcnt(0)" ::: "memory");                    \
        __builtin_amdgcn_s_barrier();                                         \
        __builtin_amdgcn_sched_barrier(0);                                    \
        const short8 bf0_ = *reinterpret_cast<const short8*>(&bfS[(P) & 1][0][nh][lane * 8]); \
        const short8 bf1_ = *reinterpret_cast<const short8*>(&bfS[(P) & 1][1][nh][lane * 8]); \
        acc[0] = __builtin_amdgcn_mfma_f32_32x32x16_bf16(Ac[0], bf0_, acc[0], 0, 0, 0); \
        acc[1] = __builtin_amdgcn_mfma_f32_32x32x16_bf16(Ac[1], bf0_, acc[1], 0, 0, 0); \
        acc[2] = __builtin_amdgcn_mfma_f32_32x32x16_bf16(Ac[2], bf0_, acc[2], 0, 0, 0); \
        acc[0] = __builtin_amdgcn_mfma_f32_32x32x16_bf16(Ac[3], bf1_, acc[0], 0, 0, 0); \
        acc[1] = __builtin_amdgcn_mfma_f32_32x32x16_bf16(Ac[4], bf1_, acc[1], 0, 0, 0); \
        acc[2] = __builtin_amdgcn_mfma_f32_32x32x16_bf16(Ac[5], bf1_, acc[2], 0, 0, 0); \
    }

    short8 Aa[6], Ab[6];
    u32x4 Gx0, Gx1, Gx2, Gx3, Gy0, Gy1, Gy2, Gy3;
    f32x4 wGx, wGy;

    // prologue: pair 0's G (4) + A (6) -> 10 outstanding
    GISSUE(0 + mh, Gx0, Gx1, Gx2, Gx3, wGx);
    AISSUE(0, Aa);

    for (int pr = 0; pr < 54; pr += 2) {
        PAIRSTEP(pr,     Aa, Gx0, Gx1, Gx2, Gx3, wGx, Ab, Gy0, Gy1, Gy2, Gy3, wGy);
        PAIRSTEP(pr + 1, Ab, Gy0, Gy1, Gy2, Gy3, wGy, Aa, Gx0, Gx1, Gx2, Gx3, wGx);
    }
#undef PAIRSTEP
#undef AISSUE
#undef GISSUE

    const int pos_o = (i << 7) + j0 + px_a;
#pragma unroll
    for (int m = 0; m < 3; m++) {
        const int mt32 = mh * 3 + m;
#pragma unroll
        for (int reg = 0; reg < 16; reg++) {
            const int o = mt32 * 32 + (reg & 3) + ((reg >> 2) << 3) + (hi << 2);
            out[((size_t)(b * CC + o) << 14) + pos_o] = acc[m][reg] + bias[o];
        }
    }
}

// ---------------------------------------------------------------------------
extern "C" void kernel_launch(void* const* d_in, const int* in_sizes, int n_in,
                              void* d_out, int out_size, void* d_ws, size_t ws_size,
                              hipStream_t stream)
{
    const float* x_vq  = (const float*)d_in[0];
    const float* x_res = (const float*)d_in[1];
    const float* w_off = (const float*)d_in[2];
    const float* b_off = (const float*)d_in[3];
    const float* w_co  = (const float*)d_in[4];
    const float* b_co  = (const float*)d_in[5];
    const float* w_dcn = (const float*)d_in[6];
    const float* b_dcn = (const float*)d_in[7];
    float* out = (float*)d_out;

    char* ws = (char*)d_ws;
    unsigned short* xg = (unsigned short*)ws;                      // 25.17 MB
    const size_t xg_sz = (size_t)BB * 48 * HW * 8 * 2;
    unsigned short* fg = (unsigned short*)(ws + xg_sz);            // 12.58 MB
    const size_t fg_sz = (size_t)BB * 24 * HW * 8 * 2;
    float* offb = (float*)(ws + xg_sz + fg_sz);                    // 14.16 MB
    const size_t offb_sz = (size_t)BB * 108 * HW * 4;
    short* wA1 = (short*)(ws + xg_sz + fg_sz + offb_sz);           // 216*4096
    short* wA2 = wA1 + (size_t)216 * 4096;                         // 108*4096
    short* wA3 = wA2 + (size_t)108 * 4096;                         // 108*4096

    to_grp_k<<<dim3(BB * 48 * HW / 256), 256, 0, stream>>>(x_vq, x_res, xg);

    // packing. conv: k = c16*144 + tap*16 + cl -> w[o][c16*16+cl][tap]
    pack_w_k<<<(216 * 512 + 255) / 256, 256, 0, stream>>>(
        w_off, wA1, 192, 3456, 144, 144, 16, 1, 9, 216 * 512);
    pack_w_k<<<(108 * 512 + 255) / 256, 256, 0, stream>>>(
        w_co, wA2, 108, 1728, 144, 144, 16, 1, 9, 108 * 512);
    // dcn (c16-outer order): k = c16*144 + kt*16 + cl -> w[o][c16*16+cl][kt]
    pack_w_k<<<(108 * 512 + 255) / 256, 256, 0, stream>>>(
        w_dcn, wA3, 192, 1728, 144, 144, 16, 1, 9, 108 * 512);

    // conv1: xg [48 grp] -> fg [24 grp bf16], full-row blocks
    conv_g_k<3, 24, true><<<dim3(HH, BB), 256, 0, stream>>>(xg, wA1, b_off, fg, 192);
    // conv2: fg [24 grp] -> offb [108 planar f32], full-row blocks
    conv_g_k<2, 12, false><<<dim3(HH, BB), 256, 0, stream>>>(fg, wA2, b_co, offb, 108);
    // fused deform-sample + einsum (producer-split, 64-px blocks)
    dcn_g_k<<<dim3(2, HH, BB), 256, 0, stream>>>(xg, offb, wA3, b_dcn, out);
}

// Round 12
// 176.080 us; speedup vs baseline: 1.0505x; 1.0505x over previous
//
#include <hip/hip_runtime.h>
#include <hip/hip_bf16.h>
#include <math.h>

#define HH 128
#define WW 128
#define HW 16384
#define BB 2
#define CC 192

typedef __attribute__((ext_vector_type(8)))  short short8;
typedef __attribute__((ext_vector_type(4)))  float f32x4;
typedef __attribute__((ext_vector_type(16))) float f32x16;
typedef __attribute__((ext_vector_type(2)))  float f32x2;
typedef __attribute__((ext_vector_type(4)))  unsigned u32x4;

// f32 -> bf16 bits, round-to-nearest-even
static __device__ __forceinline__ short f2bf(float f) {
    unsigned u = __float_as_uint(f);
    unsigned r = (u + 0x7FFFu + ((u >> 16) & 1u)) >> 16;
    return (short)r;
}
// u32 of 2 bf16 -> f32x2 {lo, hi}
static __device__ __forceinline__ f32x2 unpk(unsigned u) {
    f32x2 r;
    r[0] = __uint_as_float(u << 16);
    r[1] = __uint_as_float(u & 0xFFFF0000u);
    return r;
}

// async global->LDS, 16B per lane. lds dest: wave-uniform base + lane*16.
static __device__ __forceinline__ void gl_lds16(const short* gsrc, short* ldst) {
    __builtin_amdgcn_global_load_lds(
        (const __attribute__((address_space(1))) unsigned*)gsrc,
        (__attribute__((address_space(3))) unsigned*)ldst, 16, 0, 0);
}

// ---------------------------------------------------------------------------
// Grouped channels-last transpose: xg[b][cg(48)][pos][8ch] bf16.
// ---------------------------------------------------------------------------
__global__ __launch_bounds__(256) void to_grp_k(
    const float* __restrict__ xv, const float* __restrict__ xr,
    unsigned short* __restrict__ xg)
{
    const int idx = blockIdx.x * 256 + threadIdx.x;   // (b*48+cg)*HW + pos
    const int pos = idx & (HW - 1);
    const int cgb = idx >> 14;
    const int cg  = cgb % 48;
    const int b   = cgb / 48;
    short8 v;
#pragma unroll
    for (int r = 0; r < 8; r++) {
        const int c = cg * 8 + r;
        const float f = (c < 192)
            ? xv[((size_t)(b * 192 + c) << 14) + pos]
            : xr[((size_t)(b * 192 + (c - 192)) << 14) + pos];
        v[r] = f2bf(f);
    }
    *reinterpret_cast<short8*>(xg + (size_t)idx * 8) = v;
}

// ---------------------------------------------------------------------------
// Pack f32 weights into 32x32x16 A-frag chunks of 8 KB:
// wp[chunk*4096 + slot*512 + lane*8 + r], o = slot*32+(lane&31),
// k = chunk*16 + (lane>>5)*8 + r; src = w[o*so + (k/d1)*s1
//      + ((k%d1)/d2)*s2 + ((k%d1)%d2)*s3]. Zero-pad o >= Co.
// ---------------------------------------------------------------------------
__global__ void pack_w_k(const float* __restrict__ w, short* __restrict__ wp,
                         int Co, int so, int d1, int s1, int d2, int s2, int s3,
                         int total)
{
    const int idx = blockIdx.x * blockDim.x + threadIdx.x;
    if (idx >= total) return;
    const int lane  = idx & 63;
    const int slot  = (idx >> 6) & 7;
    const int chunk = idx >> 9;
    const int o     = slot * 32 + (lane & 31);
    const int k0    = chunk * 16 + ((lane >> 5) << 3);
    short8 v;
#pragma unroll
    for (int r = 0; r < 8; r++) {
        const int k = k0 + r;
        float f = 0.f;
        if (o < Co) {
            const int rem = k % d1;
            f = w[(size_t)o * so + (k / d1) * s1 + (rem / d2) * s2 + (rem % d2) * s3];
        }
        v[r] = f2bf(f);
    }
    *reinterpret_cast<short8*>(wp + (size_t)idx * 8) = v;
}

// ---------------------------------------------------------------------------
// 3x3 conv (pad 1), implicit GEMM, 32x32x16 MFMA, grouped-CL input.
// Block = 256 thr (4 waves: mg=wid>>1, nt=wid&1), 64 px per (b,i,j0);
// grid 512 -> 2 independent blocks/CU (fills each other's barrier stalls).
// SUPERSTEP of 4 chunks per barrier: ping-pong 16KB LDS superbuffers,
// B prefetched 1 superstep ahead (named ping-pong sets). Accounting at the
// vmcnt (before stage issue): in flight = B(P)4 + S(P)(4|8) + B(P+1)4;
// keep only B(P+1) -> uniform vmcnt(4) for both convs. Barriers halved vs
// pair scheme; 4*MTW MFMA per barrier.
// ---------------------------------------------------------------------------
template<int MTW, int NC16, bool OUT_GRP>
__global__ __launch_bounds__(256, 2) void conv_g_k(
    const unsigned short* __restrict__ xg,
    const short* __restrict__ wA, const float* __restrict__ bias,
    void* __restrict__ outp, int Cout)
{
    __shared__ __align__(16) short Pbuf[2][4][4096];   // 64 KB

    const int t    = threadIdx.x;
    const int lane = t & 63;
    const int wid  = t >> 6;
    const int mg   = wid >> 1;
    const int nt   = wid & 1;
    // XCD swizzle: nwg = 2*HH*BB = 512
    const int lin  = (blockIdx.z * HH + blockIdx.y) * 2 + blockIdx.x;
    const int og_  = (lin & 7) * 64 + (lin >> 3);
    const int j0   = (og_ & 1) * 64;
    const int i    = (og_ >> 1) & (HH - 1);
    const int b    = og_ >> 8;
    const int px   = j0 + (nt << 5) + (lane & 31);
    const int hi   = lane >> 5;
    constexpr int NQ = NC16 * 9;
    constexpr int NS = NQ / 4;           // 54 (conv1) / 27 (conv2)

    const unsigned short* __restrict__ xgb = xg + (size_t)b * (NC16 * 2) * HW * 8;

    f32x16 acc[MTW];
#pragma unroll
    for (int m = 0; m < MTW; m++)
#pragma unroll
        for (int r = 0; r < 16; r++) acc[m][r] = 0.f;

    auto loadB = [&](int qq, short8& dst, bool& vm) {
        const int c16 = qq / 9;
        const int tap = qq - c16 * 9;
        const int iy  = i + tap / 3 - 1;
        const int jx  = px + tap % 3 - 1;
        vm = ((unsigned)iy < HH) && ((unsigned)jx < WW);
        const int iyc = min(max(iy, 0), HH - 1);
        const int jxc = min(max(jx, 0), WW - 1);
        dst = *reinterpret_cast<const short8*>(
            xgb + ((size_t)(c16 * 2 + hi) * HW + (iyc << 7) + jxc) * 8);
    };
    // stage chunk into Pbuf[buf][sl]; MTW=2 uses only slots 0..3 -> 1 gl_lds
    auto stage = [&](int chunk, int buf, int sl) {
        gl_lds16(wA + (size_t)chunk * 4096 + t * 8, &Pbuf[buf][sl][wid * 512]);
        if constexpr (MTW >= 3)
            gl_lds16(wA + (size_t)chunk * 4096 + (t + 256) * 8,
                     &Pbuf[buf][sl][2048 + wid * 512]);
    };

#define LOADB4(P, Bset, Mset)                                                 \
    {                                                                         \
        loadB(min(4 * (P) + 0, NQ - 1), Bset[0], Mset[0]);                    \
        loadB(min(4 * (P) + 1, NQ - 1), Bset[1], Mset[1]);                    \
        loadB(min(4 * (P) + 2, NQ - 1), Bset[2], Mset[2]);                    \
        loadB(min(4 * (P) + 3, NQ - 1), Bset[3], Mset[3]);                    \
    }
#define STAGE4(P, BUFI)                                                       \
    {                                                                         \
        stage(min(4 * (P) + 0, NQ - 1), BUFI, 0);                             \
        stage(min(4 * (P) + 1, NQ - 1), BUFI, 1);                             \
        stage(min(4 * (P) + 2, NQ - 1), BUFI, 2);                             \
        stage(min(4 * (P) + 3, NQ - 1), BUFI, 3);                             \
    }

    short8 Bs0[4], Bs1[4];
    bool   Ms0[4], Ms1[4];

    // prologue: S(0) then B(0) -> in flight S0 + B0
    STAGE4(0, 0);
    LOADB4(0, Bs0, Ms0);

#define CCHUNK4(BUFI, C, Bset, Mset)                                          \
    {                                                                         \
        short8 bF = Bset[C];                                                  \
        if (!Mset[C]) { _Pragma("unroll")                                     \
            for (int r = 0; r < 8; r++) bF[r] = 0; }                          \
        const short* ab_ = &Pbuf[BUFI][C][(mg * MTW) * 512 + lane * 8];       \
        short8 aF[MTW];                                                       \
        _Pragma("unroll")                                                     \
        for (int m = 0; m < MTW; m++)                                         \
            aF[m] = *reinterpret_cast<const short8*>(ab_ + m * 512);          \
        _Pragma("unroll")                                                     \
        for (int m = 0; m < MTW; m++)                                         \
            acc[m] = __builtin_amdgcn_mfma_f32_32x32x16_bf16(aF[m], bF, acc[m], 0, 0, 0); \
    }

#define SSTEP(P, BUFI, Bc, Mc, Bn, Mn)                                        \
    {                                                                         \
        const int pn_ = min((P) + 1, NS - 1);                                 \
        LOADB4(pn_, Bn, Mn);                                                  \
        asm volatile("s_waitcnt vmcnt(4)" ::: "memory");                      \
        __builtin_amdgcn_s_barrier();                                         \
        __builtin_amdgcn_sched_barrier(0);                                    \
        STAGE4(pn_, (BUFI) ^ 1);                                              \
        CCHUNK4(BUFI, 0, Bc, Mc);                                             \
        CCHUNK4(BUFI, 1, Bc, Mc);                                             \
        CCHUNK4(BUFI, 2, Bc, Mc);                                             \
        CCHUNK4(BUFI, 3, Bc, Mc);                                             \
    }

    for (int pp = 0; pp < NS; pp += 2) {
        SSTEP(pp, 0, Bs0, Ms0, Bs1, Ms1);
        if (pp + 1 < NS) SSTEP(pp + 1, 1, Bs1, Ms1, Bs0, Ms0);
    }
#undef SSTEP
#undef CCHUNK4
#undef STAGE4
#undef LOADB4

    // store. C/D: col = lane&31 -> px ; row = (reg&3)+8*(reg>>2)+4*hi -> o.
    const int pos_o = (i << 7) + px;
    if constexpr (OUT_GRP) {
        unsigned short* fg = (unsigned short*)outp;
#pragma unroll
        for (int m = 0; m < MTW; m++) {
            const int mt32 = mg * MTW + m;
#pragma unroll
            for (int g = 0; g < 4; g++) {
                const int ob = mt32 * 32 + 8 * g + 4 * hi;
                const unsigned s0 = (unsigned short)f2bf(acc[m][4 * g + 0] + bias[ob + 0]);
                const unsigned s1 = (unsigned short)f2bf(acc[m][4 * g + 1] + bias[ob + 1]);
                const unsigned s2 = (unsigned short)f2bf(acc[m][4 * g + 2] + bias[ob + 2]);
                const unsigned s3 = (unsigned short)f2bf(acc[m][4 * g + 3] + bias[ob + 3]);
                const int cg = mt32 * 4 + g;
                *reinterpret_cast<uint2*>(
                    fg + ((size_t)(b * (Cout >> 3) + cg) * HW + pos_o) * 8 + 4 * hi) =
                    make_uint2(s0 | (s1 << 16), s2 | (s3 << 16));
            }
        }
    } else {
        float* of = (float*)outp;
#pragma unroll
        for (int m = 0; m < MTW; m++) {
            const int mt32 = mg * MTW + m;
#pragma unroll
            for (int reg = 0; reg < 16; reg++) {
                const int o = mt32 * 32 + (reg & 3) + ((reg >> 2) << 3) + (hi << 2);
                if (o < Cout)
                    of[((size_t)(b * Cout + o) << 14) + pos_o] = acc[m][reg] + bias[o];
            }
        }
    }
}

// ---------------------------------------------------------------------------
// Fused deform-sample + einsum, 32x32x16 MFMA, producer-split bF sharing.
// (Round-10 verbatim — best measured.) Block = 128 thr (2 waves), 32 px x
// 192 out-ch; grid 1024 -> 4 blocks/CU. Pair scheme: wave w gathers+combines
// chunk 2P+w only, writes bF to double-buffered LDS; one raw s_barrier per
// pair (global prefetches stay in flight); both waves MFMA both sub-chunks
// for their m-half. Per pair per wave issue: 4 G + 6 A -> exact vmcnt(10).
// ---------------------------------------------------------------------------
__global__ __launch_bounds__(128, 2) void dcn_g_k(
    const unsigned short* __restrict__ xg, const float* __restrict__ off,
    const short* __restrict__ wA, const float* __restrict__ bias,
    float* __restrict__ out)
{
    __shared__ __align__(16) f32x4 eW[1152];      // 18.4 KB (36 gk x 32 px)
    __shared__ __align__(8)  uint2 eO[1152];      //  9.2 KB
    __shared__ __align__(16) short bfS[2][2][512];//  4 KB  [buf][subchunk][.]

    const int t    = threadIdx.x;
    const int lane = t & 63;
    const int w    = t >> 6;     // wave id = producer sub-chunk = m-half
    // XCD swizzle: nwg = 4*HH*BB = 1024
    const int lin  = (blockIdx.z * HH + blockIdx.y) * 4 + blockIdx.x;
    const int og_  = (lin & 7) * 128 + (lin >> 3);
    const int jt   = og_ & 3;
    const int i    = (og_ >> 2) & (HH - 1);
    const int b    = og_ >> 9;
    const int j0   = jt * 32;

    // ---- A1: bilinear entries (identical math to verified rounds 2-11) ----
    for (int e = t; e < 1152; e += 128) {
        const int p  = e & 31;
        const int gk = e >> 5;               // g*9 + kt
        const int kt = gk % 9;
        const int j  = j0 + p;
        const size_t sp = (size_t)b * 108 * HW + (size_t)gk * HW + (i << 7) + j;
        const float dy = off[sp];
        const float dx = off[sp + (size_t)36 * HW];
        const float mv = off[sp + (size_t)72 * HW];
        const float m  = 1.f / (1.f + expf(-mv));
        const float py = (float)(i + kt / 3 - 1) + dy;
        const float px = (float)(j + kt % 3 - 1) + dx;
        const float y0f = floorf(py), x0f = floorf(px);
        const float ly = py - y0f, lx = px - x0f;
        const int y0 = (int)y0f, x0 = (int)x0f;
        const float vy0 = (y0 >= 0 && y0 < HH) ? 1.f : 0.f;
        const float vy1 = (y0 + 1 >= 0 && y0 + 1 < HH) ? 1.f : 0.f;
        const float vx0 = (x0 >= 0 && x0 < WW) ? 1.f : 0.f;
        const float vx1 = (x0 + 1 >= 0 && x0 + 1 < WW) ? 1.f : 0.f;
        f32x4 w4;
        w4[0] = (1.f - ly) * (1.f - lx) * m * vy0 * vx0;
        w4[1] = (1.f - ly) * lx         * m * vy0 * vx1;
        w4[2] = ly         * (1.f - lx) * m * vy1 * vx0;
        w4[3] = ly         * lx         * m * vy1 * vx1;
        const int yc0 = min(max(y0, 0), HH - 1);
        const int yc1 = min(max(y0 + 1, 0), HH - 1);
        const int xc0 = min(max(x0, 0), WW - 1);
        const int xc1 = min(max(x0 + 1, 0), WW - 1);
        eW[e] = w4;
        eO[e] = make_uint2((unsigned)((yc0 << 7) + xc0) | ((unsigned)((yc0 << 7) + xc1) << 16),
                           (unsigned)((yc1 << 7) + xc0) | ((unsigned)((yc1 << 7) + xc1) << 16));
    }
    __syncthreads();

    const int px_l = lane & 31;
    const int hi   = lane >> 5;
    const unsigned short* __restrict__ xgb = xg + (size_t)b * 48 * HW * 8;

    f32x16 acc[3];
#pragma unroll
    for (int m = 0; m < 3; m++)
#pragma unroll
        for (int r = 0; r < 16; r++) acc[m][r] = 0.f;

    // my gather chunk for pair P is 2P + w
#define GISSUE(QQ, N0, N1, N2, N3, WN)                                        \
    {                                                                         \
        const int qn_   = min((QQ), 107);                                     \
        const int c16n_ = qn_ / 9;                                            \
        const int ktn_  = qn_ - 9 * c16n_;                                    \
        const int e_    = ((c16n_ / 3) * 9 + ktn_) * 32 + px_l;               \
        const uint2 o_  = eO[e_];                                             \
        WN = eW[e_];                                                          \
        const unsigned short* base_ = xgb + (size_t)(c16n_ * 2 + hi) * (HW * 8); \
        N0 = *reinterpret_cast<const u32x4*>(base_ + (size_t)(o_.x & 0xFFFFu) * 8); \
        N1 = *reinterpret_cast<const u32x4*>(base_ + (size_t)(o_.x >> 16) * 8);     \
        N2 = *reinterpret_cast<const u32x4*>(base_ + (size_t)(o_.y & 0xFFFFu) * 8); \
        N3 = *reinterpret_cast<const u32x4*>(base_ + (size_t)(o_.y >> 16) * 8);     \
    }

    // A frags for pair P (chunks 2P, 2P+1), m-half w: 6 b128 loads
#define AISSUE(PP, DST)                                                       \
    {                                                                         \
        const short* a0_ = wA + (size_t)min(2 * (PP),     107) * 4096 + (w * 3) * 512 + lane * 8; \
        const short* a1_ = wA + (size_t)min(2 * (PP) + 1, 107) * 4096 + (w * 3) * 512 + lane * 8; \
        DST[0] = *reinterpret_cast<const short8*>(a0_);                       \
        DST[1] = *reinterpret_cast<const short8*>(a0_ + 512);                 \
        DST[2] = *reinterpret_cast<const short8*>(a0_ + 1024);                \
        DST[3] = *reinterpret_cast<const short8*>(a1_);                       \
        DST[4] = *reinterpret_cast<const short8*>(a1_ + 512);                 \
        DST[5] = *reinterpret_cast<const short8*>(a1_ + 1024);                \
    }

#define PAIRSTEP(P, Ac, C0, C1, C2, C3, WC, An, N0, N1, N2, N3, WN)           \
    {                                                                         \
        GISSUE(2 * ((P) + 1) + w, N0, N1, N2, N3, WN);                        \
        AISSUE((P) + 1, An);                                                  \
        asm volatile("s_waitcnt vmcnt(10)" ::: "memory");                     \
        u32x4 rv_;                                                            \
        _Pragma("unroll")                                                     \
        for (int jj = 0; jj < 4; jj++) {                                      \
            f32x2 v_ = WC[0] * unpk(C0[jj]) + WC[1] * unpk(C1[jj])            \
                     + WC[2] * unpk(C2[jj]) + WC[3] * unpk(C3[jj]);           \
            __hip_bfloat162 h2_ = __float22bfloat162_rn(make_float2(v_[0], v_[1])); \
            unsigned hu_; __builtin_memcpy(&hu_, &h2_, 4);                    \
            rv_[jj] = hu_;                                                    \
        }                                                                     \
        *reinterpret_cast<u32x4*>(&bfS[(P) & 1][w][lane * 8]) = rv_;          \
        asm volatile("s_waitcnt lgkmcnt(0)" ::: "memory");                    \
        __builtin_amdgcn_s_barrier();                                         \
        __builtin_amdgcn_sched_barrier(0);                                    \
        const short8 bf0_ = *reinterpret_cast<const short8*>(&bfS[(P) & 1][0][lane * 8]); \
        const short8 bf1_ = *reinterpret_cast<const short8*>(&bfS[(P) & 1][1][lane * 8]); \
        acc[0] = __builtin_amdgcn_mfma_f32_32x32x16_bf16(Ac[0], bf0_, acc[0], 0, 0, 0); \
        acc[1] = __builtin_amdgcn_mfma_f32_32x32x16_bf16(Ac[1], bf0_, acc[1], 0, 0, 0); \
        acc[2] = __builtin_amdgcn_mfma_f32_32x32x16_bf16(Ac[2], bf0_, acc[2], 0, 0, 0); \
        acc[0] = __builtin_amdgcn_mfma_f32_32x32x16_bf16(Ac[3], bf1_, acc[0], 0, 0, 0); \
        acc[1] = __builtin_amdgcn_mfma_f32_32x32x16_bf16(Ac[4], bf1_, acc[1], 0, 0, 0); \
        acc[2] = __builtin_amdgcn_mfma_f32_32x32x16_bf16(Ac[5], bf1_, acc[2], 0, 0, 0); \
    }

    short8 Aa[6], Ab[6];
    u32x4 Gx0, Gx1, Gx2, Gx3, Gy0, Gy1, Gy2, Gy3;
    f32x4 wGx, wGy;

    // prologue: pair 0's G (4) + A (6) -> 10 outstanding
    GISSUE(0 + w, Gx0, Gx1, Gx2, Gx3, wGx);
    AISSUE(0, Aa);

    for (int pr = 0; pr < 54; pr += 2) {
        PAIRSTEP(pr,     Aa, Gx0, Gx1, Gx2, Gx3, wGx, Ab, Gy0, Gy1, Gy2, Gy3, wGy);
        PAIRSTEP(pr + 1, Ab, Gy0, Gy1, Gy2, Gy3, wGy, Aa, Gx0, Gx1, Gx2, Gx3, wGx);
    }
#undef PAIRSTEP
#undef AISSUE
#undef GISSUE

    const int pos_o = (i << 7) + j0 + px_l;
#pragma unroll
    for (int m = 0; m < 3; m++) {
        const int mt32 = w * 3 + m;
#pragma unroll
        for (int reg = 0; reg < 16; reg++) {
            const int o = mt32 * 32 + (reg & 3) + ((reg >> 2) << 3) + (hi << 2);
            out[((size_t)(b * CC + o) << 14) + pos_o] = acc[m][reg] + bias[o];
        }
    }
}

// ---------------------------------------------------------------------------
extern "C" void kernel_launch(void* const* d_in, const int* in_sizes, int n_in,
                              void* d_out, int out_size, void* d_ws, size_t ws_size,
                              hipStream_t stream)
{
    const float* x_vq  = (const float*)d_in[0];
    const float* x_res = (const float*)d_in[1];
    const float* w_off = (const float*)d_in[2];
    const float* b_off = (const float*)d_in[3];
    const float* w_co  = (const float*)d_in[4];
    const float* b_co  = (const float*)d_in[5];
    const float* w_dcn = (const float*)d_in[6];
    const float* b_dcn = (const float*)d_in[7];
    float* out = (float*)d_out;

    char* ws = (char*)d_ws;
    unsigned short* xg = (unsigned short*)ws;                      // 25.17 MB
    const size_t xg_sz = (size_t)BB * 48 * HW * 8 * 2;
    unsigned short* fg = (unsigned short*)(ws + xg_sz);            // 12.58 MB
    const size_t fg_sz = (size_t)BB * 24 * HW * 8 * 2;
    float* offb = (float*)(ws + xg_sz + fg_sz);                    // 14.16 MB
    const size_t offb_sz = (size_t)BB * 108 * HW * 4;
    short* wA1 = (short*)(ws + xg_sz + fg_sz + offb_sz);           // 216*4096
    short* wA2 = wA1 + (size_t)216 * 4096;                         // 108*4096
    short* wA3 = wA2 + (size_t)108 * 4096;                         // 108*4096

    to_grp_k<<<dim3(BB * 48 * HW / 256), 256, 0, stream>>>(x_vq, x_res, xg);

    // packing. conv: k = c16*144 + tap*16 + cl -> w[o][c16*16+cl][tap]
    pack_w_k<<<(216 * 512 + 255) / 256, 256, 0, stream>>>(
        w_off, wA1, 192, 3456, 144, 144, 16, 1, 9, 216 * 512);
    pack_w_k<<<(108 * 512 + 255) / 256, 256, 0, stream>>>(
        w_co, wA2, 108, 1728, 144, 144, 16, 1, 9, 108 * 512);
    // dcn (c16-outer order): k = c16*144 + kt*16 + cl -> w[o][c16*16+cl][kt]
    pack_w_k<<<(108 * 512 + 255) / 256, 256, 0, stream>>>(
        w_dcn, wA3, 192, 1728, 144, 144, 16, 1, 9, 108 * 512);

    // conv1: xg [48 grp] -> fg [24 grp bf16]
    conv_g_k<3, 24, true><<<dim3(2, HH, BB), 256, 0, stream>>>(xg, wA1, b_off, fg, 192);
    // conv2: fg [24 grp] -> offb [108 planar f32]
    conv_g_k<2, 12, false><<<dim3(2, HH, BB), 256, 0, stream>>>(fg, wA2, b_co, offb, 108);
    // fused deform-sample + einsum (producer-split, round-10 verbatim)
    dcn_g_k<<<dim3(4, HH, BB), 128, 0, stream>>>(xg, offb, wA3, b_dcn, out);
}

// Round 14
// 174.244 us; speedup vs baseline: 1.0616x; 1.0105x over previous
//
#include <hip/hip_runtime.h>
#include <hip/hip_bf16.h>
#include <math.h>

#define HH 128
#define WW 128
#define HW 16384
#define BB 2
#define CC 192

typedef __attribute__((ext_vector_type(8)))  short short8;
typedef __attribute__((ext_vector_type(4)))  float f32x4;
typedef __attribute__((ext_vector_type(16))) float f32x16;
typedef __attribute__((ext_vector_type(2)))  float f32x2;
typedef __attribute__((ext_vector_type(4)))  unsigned u32x4;

// f32 -> bf16 bits, round-to-nearest-even
static __device__ __forceinline__ short f2bf(float f) {
    unsigned u = __float_as_uint(f);
    unsigned r = (u + 0x7FFFu + ((u >> 16) & 1u)) >> 16;
    return (short)r;
}
// u32 of 2 bf16 -> f32x2 {lo, hi}
static __device__ __forceinline__ f32x2 unpk(unsigned u) {
    f32x2 r;
    r[0] = __uint_as_float(u << 16);
    r[1] = __uint_as_float(u & 0xFFFF0000u);
    return r;
}

// async global->LDS, 16B per lane. lds dest: wave-uniform base + lane*16.
static __device__ __forceinline__ void gl_lds16(const short* gsrc, short* ldst) {
    __builtin_amdgcn_global_load_lds(
        (const __attribute__((address_space(1))) unsigned*)gsrc,
        (__attribute__((address_space(3))) unsigned*)ldst, 16, 0, 0);
}

// ---------------------------------------------------------------------------
// Grouped channels-last transpose: xg[b][cg(48)][pos][8ch] bf16.
// ---------------------------------------------------------------------------
__global__ __launch_bounds__(256) void to_grp_k(
    const float* __restrict__ xv, const float* __restrict__ xr,
    unsigned short* __restrict__ xg)
{
    const int idx = blockIdx.x * 256 + threadIdx.x;   // (b*48+cg)*HW + pos
    const int pos = idx & (HW - 1);
    const int cgb = idx >> 14;
    const int cg  = cgb % 48;
    const int b   = cgb / 48;
    short8 v;
#pragma unroll
    for (int r = 0; r < 8; r++) {
        const int c = cg * 8 + r;
        const float f = (c < 192)
            ? xv[((size_t)(b * 192 + c) << 14) + pos]
            : xr[((size_t)(b * 192 + (c - 192)) << 14) + pos];
        v[r] = f2bf(f);
    }
    *reinterpret_cast<short8*>(xg + (size_t)idx * 8) = v;
}

// ---------------------------------------------------------------------------
// Pack f32 weights into 32x32x16 A-frag chunks of 8 KB:
// wp[chunk*4096 + slot*512 + lane*8 + r], o = slot*32+(lane&31),
// k = chunk*16 + (lane>>5)*8 + r; src = w[o*so + (k/d1)*s1
//      + ((k%d1)/d2)*s2 + ((k%d1)%d2)*s3]. Zero-pad o >= Co.
// ---------------------------------------------------------------------------
__global__ void pack_w_k(const float* __restrict__ w, short* __restrict__ wp,
                         int Co, int so, int d1, int s1, int d2, int s2, int s3,
                         int total)
{
    const int idx = blockIdx.x * blockDim.x + threadIdx.x;
    if (idx >= total) return;
    const int lane  = idx & 63;
    const int slot  = (idx >> 6) & 7;
    const int chunk = idx >> 9;
    const int o     = slot * 32 + (lane & 31);
    const int k0    = chunk * 16 + ((lane >> 5) << 3);
    short8 v;
#pragma unroll
    for (int r = 0; r < 8; r++) {
        const int k = k0 + r;
        float f = 0.f;
        if (o < Co) {
            const int rem = k % d1;
            f = w[(size_t)o * so + (k / d1) * s1 + (rem / d2) * s2 + (rem % d2) * s3];
        }
        v[r] = f2bf(f);
    }
    *reinterpret_cast<short8*>(wp + (size_t)idx * 8) = v;
}

// ---------------------------------------------------------------------------
// 3x3 conv (pad 1), implicit GEMM, 32x32x16 MFMA, grouped-CL input.
// Round-10 structure (best measured): block = 256 thr (4 waves: mg=wid>>1,
// nt=wid&1), 64 px per (b,i,j0); grid 512 -> 2 independent blocks/CU.
// TWO chunks per barrier: paired LDS buffers Pbuf[3][2][4096], 6-deep B reg
// rotation. Queue invariant at each vmcnt: [B(p+1)2, S(p+1)4, B(p+2)2] = 8
// outstanding -> vmcnt(8). NEW vs round 10: s_setprio(1) around the MFMA
// cluster (2 blocks/CU are barrier-desynced -> arbitration exists).
// ---------------------------------------------------------------------------
template<int MTW, int NC16, bool OUT_GRP>
__global__ __launch_bounds__(256, 2) void conv_g_k(
    const unsigned short* __restrict__ xg,
    const short* __restrict__ wA, const float* __restrict__ bias,
    void* __restrict__ outp, int Cout)
{
    __shared__ __align__(16) short Pbuf[3][2][4096];

    const int t    = threadIdx.x;
    const int lane = t & 63;
    const int wid  = t >> 6;
    const int mg   = wid >> 1;
    const int nt   = wid & 1;
    // XCD swizzle: nwg = 2*HH*BB = 512
    const int lin  = (blockIdx.z * HH + blockIdx.y) * 2 + blockIdx.x;
    const int og_  = (lin & 7) * 64 + (lin >> 3);
    const int j0   = (og_ & 1) * 64;
    const int i    = (og_ >> 1) & (HH - 1);
    const int b    = og_ >> 8;
    const int px   = j0 + (nt << 5) + (lane & 31);
    const int hi   = lane >> 5;
    constexpr int NQ = NC16 * 9;
    constexpr int NP = NQ / 2;   // pairs (divisible by 3)

    const unsigned short* __restrict__ xgb = xg + (size_t)b * (NC16 * 2) * HW * 8;

    f32x16 acc[MTW];
#pragma unroll
    for (int m = 0; m < MTW; m++)
#pragma unroll
        for (int r = 0; r < 16; r++) acc[m][r] = 0.f;

    auto loadB = [&](int qq, short8& dst, bool& vm) {
        const int c16 = qq / 9;
        const int tap = qq - c16 * 9;
        const int iy  = i + tap / 3 - 1;
        const int jx  = px + tap % 3 - 1;
        vm = ((unsigned)iy < HH) && ((unsigned)jx < WW);
        const int iyc = min(max(iy, 0), HH - 1);
        const int jxc = min(max(jx, 0), WW - 1);
        dst = *reinterpret_cast<const short8*>(
            xgb + ((size_t)(c16 * 2 + hi) * HW + (iyc << 7) + jxc) * 8);
    };
    auto stage2 = [&](int chunk, int pb, int sl) {
        gl_lds16(wA + (size_t)chunk * 4096 + t * 8,         &Pbuf[pb][sl][wid * 512]);
        gl_lds16(wA + (size_t)chunk * 4096 + (t + 256) * 8, &Pbuf[pb][sl][2048 + wid * 512]);
    };

    short8 B0, B1, B2, B3, B4, B5;
    bool M0, M1, M2, M3, M4, M5;

    // prologue order (queue invariant): S(pair0)4, B(pair0)2, S(pair1)4, B(pair1)2
    stage2(0, 0, 0); stage2(1, 0, 1);
    loadB(0, B0, M0); loadB(1, B1, M1);
    stage2(2, 1, 0); stage2(3, 1, 1);
    loadB(2, B2, M2); loadB(3, B3, M3);

#define CCHUNK(IBUF, SL, BC, MC)                                              \
    {                                                                         \
        short8 bF = BC;                                                       \
        if (!MC) {                                                            \
            _Pragma("unroll")                                                 \
            for (int r = 0; r < 8; r++) bF[r] = 0;                            \
        }                                                                     \
        const short* ab_ = &Pbuf[IBUF][SL][(mg * MTW) * 512 + lane * 8];      \
        short8 aF[MTW];                                                       \
        _Pragma("unroll")                                                     \
        for (int m = 0; m < MTW; m++)                                         \
            aF[m] = *reinterpret_cast<const short8*>(ab_ + m * 512);          \
        __builtin_amdgcn_s_setprio(1);                                        \
        _Pragma("unroll")                                                     \
        for (int m = 0; m < MTW; m++)                                         \
            acc[m] = __builtin_amdgcn_mfma_f32_32x32x16_bf16(aF[m], bF, acc[m], 0, 0, 0); \
        __builtin_amdgcn_s_setprio(0);                                        \
    }

#define PSTEP(P, IBUF, SBUF, Bc0, Mc0, Bc1, Mc1, Bn0, Mn0, Bn1, Mn1)          \
    {                                                                         \
        loadB(min(2 * ((P) + 2),     NQ - 1), Bn0, Mn0);                      \
        loadB(min(2 * ((P) + 2) + 1, NQ - 1), Bn1, Mn1);                      \
        asm volatile("s_waitcnt vmcnt(8)" ::: "memory");                      \
        __builtin_amdgcn_s_barrier();                                         \
        __builtin_amdgcn_sched_barrier(0);                                    \
        const int sc0_ = min(2 * ((P) + 2),     NQ - 1);                      \
        const int sc1_ = min(2 * ((P) + 2) + 1, NQ - 1);                      \
        stage2(sc0_, SBUF, 0); stage2(sc1_, SBUF, 1);                         \
        CCHUNK(IBUF, 0, Bc0, Mc0);                                            \
        CCHUNK(IBUF, 1, Bc1, Mc1);                                            \
    }

    for (int pp = 0; pp < NP; pp += 3) {
        PSTEP(pp + 0, 0, 2, B0, M0, B1, M1, B4, M4, B5, M5);
        PSTEP(pp + 1, 1, 0, B2, M2, B3, M3, B0, M0, B1, M1);
        PSTEP(pp + 2, 2, 1, B4, M4, B5, M5, B2, M2, B3, M3);
    }
#undef PSTEP
#undef CCHUNK

    // store. C/D: col = lane&31 -> px ; row = (reg&3)+8*(reg>>2)+4*hi -> o.
    const int pos_o = (i << 7) + px;
    if constexpr (OUT_GRP) {
        unsigned short* fg = (unsigned short*)outp;
#pragma unroll
        for (int m = 0; m < MTW; m++) {
            const int mt32 = mg * MTW + m;
#pragma unroll
            for (int g = 0; g < 4; g++) {
                const int ob = mt32 * 32 + 8 * g + 4 * hi;
                const unsigned s0 = (unsigned short)f2bf(acc[m][4 * g + 0] + bias[ob + 0]);
                const unsigned s1 = (unsigned short)f2bf(acc[m][4 * g + 1] + bias[ob + 1]);
                const unsigned s2 = (unsigned short)f2bf(acc[m][4 * g + 2] + bias[ob + 2]);
                const unsigned s3 = (unsigned short)f2bf(acc[m][4 * g + 3] + bias[ob + 3]);
                const int cg = mt32 * 4 + g;
                *reinterpret_cast<uint2*>(
                    fg + ((size_t)(b * (Cout >> 3) + cg) * HW + pos_o) * 8 + 4 * hi) =
                    make_uint2(s0 | (s1 << 16), s2 | (s3 << 16));
            }
        }
    } else {
        float* of = (float*)outp;
#pragma unroll
        for (int m = 0; m < MTW; m++) {
            const int mt32 = mg * MTW + m;
#pragma unroll
            for (int reg = 0; reg < 16; reg++) {
                const int o = mt32 * 32 + (reg & 3) + ((reg >> 2) << 3) + (hi << 2);
                if (o < Cout)
                    of[((size_t)(b * Cout + o) << 14) + pos_o] = acc[m][reg] + bias[o];
            }
        }
    }
}

// ---------------------------------------------------------------------------
// Fused deform-sample + einsum, 32x32x16 MFMA, producer-split bF sharing.
// (Round-10 structure verbatim + setprio.) Block = 128 thr (2 waves),
// 32 px x 192 out-ch; grid 1024 -> 4 blocks/CU. Pair scheme: wave w
// gathers+combines chunk 2P+w only, writes bF to double-buffered LDS; one
// raw s_barrier per pair (global prefetches stay in flight); both waves
// MFMA both sub-chunks for their m-half. Per pair per wave issue:
// 4 G + 6 A -> exact vmcnt(10).
// ---------------------------------------------------------------------------
__global__ __launch_bounds__(128, 2) void dcn_g_k(
    const unsigned short* __restrict__ xg, const float* __restrict__ off,
    const short* __restrict__ wA, const float* __restrict__ bias,
    float* __restrict__ out)
{
    __shared__ __align__(16) f32x4 eW[1152];      // 18.4 KB (36 gk x 32 px)
    __shared__ __align__(8)  uint2 eO[1152];      //  9.2 KB
    __shared__ __align__(16) short bfS[2][2][512];//  4 KB  [buf][subchunk][.]

    const int t    = threadIdx.x;
    const int lane = t & 63;
    const int w    = t >> 6;     // wave id = producer sub-chunk = m-half
    // XCD swizzle: nwg = 4*HH*BB = 1024
    const int lin  = (blockIdx.z * HH + blockIdx.y) * 4 + blockIdx.x;
    const int og_  = (lin & 7) * 128 + (lin >> 3);
    const int jt   = og_ & 3;
    const int i    = (og_ >> 2) & (HH - 1);
    const int b    = og_ >> 9;
    const int j0   = jt * 32;

    // ---- A1: bilinear entries (identical math to verified rounds 2-12) ----
    for (int e = t; e < 1152; e += 128) {
        const int p  = e & 31;
        const int gk = e >> 5;               // g*9 + kt
        const int kt = gk % 9;
        const int j  = j0 + p;
        const size_t sp = (size_t)b * 108 * HW + (size_t)gk * HW + (i << 7) + j;
        const float dy = off[sp];
        const float dx = off[sp + (size_t)36 * HW];
        const float mv = off[sp + (size_t)72 * HW];
        const float m  = 1.f / (1.f + expf(-mv));
        const float py = (float)(i + kt / 3 - 1) + dy;
        const float px = (float)(j + kt % 3 - 1) + dx;
        const float y0f = floorf(py), x0f = floorf(px);
        const float ly = py - y0f, lx = px - x0f;
        const int y0 = (int)y0f, x0 = (int)x0f;
        const float vy0 = (y0 >= 0 && y0 < HH) ? 1.f : 0.f;
        const float vy1 = (y0 + 1 >= 0 && y0 + 1 < HH) ? 1.f : 0.f;
        const float vx0 = (x0 >= 0 && x0 < WW) ? 1.f : 0.f;
        const float vx1 = (x0 + 1 >= 0 && x0 + 1 < WW) ? 1.f : 0.f;
        f32x4 w4;
        w4[0] = (1.f - ly) * (1.f - lx) * m * vy0 * vx0;
        w4[1] = (1.f - ly) * lx         * m * vy0 * vx1;
        w4[2] = ly         * (1.f - lx) * m * vy1 * vx0;
        w4[3] = ly         * lx         * m * vy1 * vx1;
        const int yc0 = min(max(y0, 0), HH - 1);
        const int yc1 = min(max(y0 + 1, 0), HH - 1);
        const int xc0 = min(max(x0, 0), WW - 1);
        const int xc1 = min(max(x0 + 1, 0), WW - 1);
        eW[e] = w4;
        eO[e] = make_uint2((unsigned)((yc0 << 7) + xc0) | ((unsigned)((yc0 << 7) + xc1) << 16),
                           (unsigned)((yc1 << 7) + xc0) | ((unsigned)((yc1 << 7) + xc1) << 16));
    }
    __syncthreads();

    const int px_l = lane & 31;
    const int hi   = lane >> 5;
    const unsigned short* __restrict__ xgb = xg + (size_t)b * 48 * HW * 8;

    f32x16 acc[3];
#pragma unroll
    for (int m = 0; m < 3; m++)
#pragma unroll
        for (int r = 0; r < 16; r++) acc[m][r] = 0.f;

    // my gather chunk for pair P is 2P + w
#define GISSUE(QQ, N0, N1, N2, N3, WN)                                        \
    {                                                                         \
        const int qn_   = min((QQ), 107);                                     \
        const int c16n_ = qn_ / 9;                                            \
        const int ktn_  = qn_ - 9 * c16n_;                                    \
        const int e_    = ((c16n_ / 3) * 9 + ktn_) * 32 + px_l;               \
        const uint2 o_  = eO[e_];                                             \
        WN = eW[e_];                                                          \
        const unsigned short* base_ = xgb + (size_t)(c16n_ * 2 + hi) * (HW * 8); \
        N0 = *reinterpret_cast<const u32x4*>(base_ + (size_t)(o_.x & 0xFFFFu) * 8); \
        N1 = *reinterpret_cast<const u32x4*>(base_ + (size_t)(o_.x >> 16) * 8);     \
        N2 = *reinterpret_cast<const u32x4*>(base_ + (size_t)(o_.y & 0xFFFFu) * 8); \
        N3 = *reinterpret_cast<const u32x4*>(base_ + (size_t)(o_.y >> 16) * 8);     \
    }

    // A frags for pair P (chunks 2P, 2P+1), m-half w: 6 b128 loads
#define AISSUE(PP, DST)                                                       \
    {                                                                         \
        const short* a0_ = wA + (size_t)min(2 * (PP),     107) * 4096 + (w * 3) * 512 + lane * 8; \
        const short* a1_ = wA + (size_t)min(2 * (PP) + 1, 107) * 4096 + (w * 3) * 512 + lane * 8; \
        DST[0] = *reinterpret_cast<const short8*>(a0_);                       \
        DST[1] = *reinterpret_cast<const short8*>(a0_ + 512);                 \
        DST[2] = *reinterpret_cast<const short8*>(a0_ + 1024);                \
        DST[3] = *reinterpret_cast<const short8*>(a1_);                       \
        DST[4] = *reinterpret_cast<const short8*>(a1_ + 512);                 \
        DST[5] = *reinterpret_cast<const short8*>(a1_ + 1024);                \
    }

#define PAIRSTEP(P, Ac, C0, C1, C2, C3, WC, An, N0, N1, N2, N3, WN)           \
    {                                                                         \
        GISSUE(2 * ((P) + 1) + w, N0, N1, N2, N3, WN);                        \
        AISSUE((P) + 1, An);                                                  \
        asm volatile("s_waitcnt vmcnt(10)" ::: "memory");                     \
        u32x4 rv_;                                                            \
        _Pragma("unroll")                                                     \
        for (int jj = 0; jj < 4; jj++) {                                      \
            f32x2 v_ = WC[0] * unpk(C0[jj]) + WC[1] * unpk(C1[jj])            \
                     + WC[2] * unpk(C2[jj]) + WC[3] * unpk(C3[jj]);           \
            __hip_bfloat162 h2_ = __float22bfloat162_rn(make_float2(v_[0], v_[1])); \
            unsigned hu_; __builtin_memcpy(&hu_, &h2_, 4);                    \
            rv_[jj] = hu_;                                                    \
        }                                                                     \
        *reinterpret_cast<u32x4*>(&bfS[(P) & 1][w][lane * 8]) = rv_;          \
        asm volatile("s_waitcnt lgkmcnt(0)" ::: "memory");                    \
        __builtin_amdgcn_s_barrier();                                         \
        __builtin_amdgcn_sched_barrier(0);                                    \
        const short8 bf0_ = *reinterpret_cast<const short8*>(&bfS[(P) & 1][0][lane * 8]); \
        const short8 bf1_ = *reinterpret_cast<const short8*>(&bfS[(P) & 1][1][lane * 8]); \
        __builtin_amdgcn_s_setprio(1);                                        \
        acc[0] = __builtin_amdgcn_mfma_f32_32x32x16_bf16(Ac[0], bf0_, acc[0], 0, 0, 0); \
        acc[1] = __builtin_amdgcn_mfma_f32_32x32x16_bf16(Ac[1], bf0_, acc[1], 0, 0, 0); \
        acc[2] = __builtin_amdgcn_mfma_f32_32x32x16_bf16(Ac[2], bf0_, acc[2], 0, 0, 0); \
        acc[0] = __builtin_amdgcn_mfma_f32_32x32x16_bf16(Ac[3], bf1_, acc[0], 0, 0, 0); \
        acc[1] = __builtin_amdgcn_mfma_f32_32x32x16_bf16(Ac[4], bf1_, acc[1], 0, 0, 0); \
        acc[2] = __builtin_amdgcn_mfma_f32_32x32x16_bf16(Ac[5], bf1_, acc[2], 0, 0, 0); \
        __builtin_amdgcn_s_setprio(0);                                        \
    }

    short8 Aa[6], Ab[6];
    u32x4 Gx0, Gx1, Gx2, Gx3, Gy0, Gy1, Gy2, Gy3;
    f32x4 wGx, wGy;

    // prologue: pair 0's G (4) + A (6) -> 10 outstanding
    GISSUE(0 + w, Gx0, Gx1, Gx2, Gx3, wGx);
    AISSUE(0, Aa);

    for (int pr = 0; pr < 54; pr += 2) {
        PAIRSTEP(pr,     Aa, Gx0, Gx1, Gx2, Gx3, wGx, Ab, Gy0, Gy1, Gy2, Gy3, wGy);
        PAIRSTEP(pr + 1, Ab, Gy0, Gy1, Gy2, Gy3, wGy, Aa, Gx0, Gx1, Gx2, Gx3, wGx);
    }
#undef PAIRSTEP
#undef AISSUE
#undef GISSUE

    const int pos_o = (i << 7) + j0 + px_l;
#pragma unroll
    for (int m = 0; m < 3; m++) {
        const int mt32 = w * 3 + m;
#pragma unroll
        for (int reg = 0; reg < 16; reg++) {
            const int o = mt32 * 32 + (reg & 3) + ((reg >> 2) << 3) + (hi << 2);
            out[((size_t)(b * CC + o) << 14) + pos_o] = acc[m][reg] + bias[o];
        }
    }
}

// ---------------------------------------------------------------------------
extern "C" void kernel_launch(void* const* d_in, const int* in_sizes, int n_in,
                              void* d_out, int out_size, void* d_ws, size_t ws_size,
                              hipStream_t stream)
{
    const float* x_vq  = (const float*)d_in[0];
    const float* x_res = (const float*)d_in[1];
    const float* w_off = (const float*)d_in[2];
    const float* b_off = (const float*)d_in[3];
    const float* w_co  = (const float*)d_in[4];
    const float* b_co  = (const float*)d_in[5];
    const float* w_dcn = (const float*)d_in[6];
    const float* b_dcn = (const float*)d_in[7];
    float* out = (float*)d_out;

    char* ws = (char*)d_ws;
    unsigned short* xg = (unsigned short*)ws;                      // 25.17 MB
    const size_t xg_sz = (size_t)BB * 48 * HW * 8 * 2;
    unsigned short* fg = (unsigned short*)(ws + xg_sz);            // 12.58 MB
    const size_t fg_sz = (size_t)BB * 24 * HW * 8 * 2;
    float* offb = (float*)(ws + xg_sz + fg_sz);                    // 14.16 MB
    const size_t offb_sz = (size_t)BB * 108 * HW * 4;
    short* wA1 = (short*)(ws + xg_sz + fg_sz + offb_sz);           // 216*4096
    short* wA2 = wA1 + (size_t)216 * 4096;                         // 108*4096
    short* wA3 = wA2 + (size_t)108 * 4096;                         // 108*4096

    to_grp_k<<<dim3(BB * 48 * HW / 256), 256, 0, stream>>>(x_vq, x_res, xg);

    // packing. conv: k = c16*144 + tap*16 + cl -> w[o][c16*16+cl][tap]
    pack_w_k<<<(216 * 512 + 255) / 256, 256, 0, stream>>>(
        w_off, wA1, 192, 3456, 144, 144, 16, 1, 9, 216 * 512);
    pack_w_k<<<(108 * 512 + 255) / 256, 256, 0, stream>>>(
        w_co, wA2, 108, 1728, 144, 144, 16, 1, 9, 108 * 512);
    // dcn (c16-outer order): k = c16*144 + kt*16 + cl -> w[o][c16*16+cl][kt]
    pack_w_k<<<(108 * 512 + 255) / 256, 256, 0, stream>>>(
        w_dcn, wA3, 192, 1728, 144, 144, 16, 1, 9, 108 * 512);

    // conv1: xg [48 grp] -> fg [24 grp bf16]
    conv_g_k<3, 24, true><<<dim3(2, HH, BB), 256, 0, stream>>>(xg, wA1, b_off, fg, 192);
    // conv2: fg [24 grp] -> offb [108 planar f32]
    conv_g_k<2, 12, false><<<dim3(2, HH, BB), 256, 0, stream>>>(fg, wA2, b_co, offb, 108);
    // fused deform-sample + einsum (producer-split, round-10 verbatim)
    dcn_g_k<<<dim3(4, HH, BB), 128, 0, stream>>>(xg, offb, wA3, b_dcn, out);
}